// Round 14
// baseline (130.805 us; speedup 1.0000x reference)
//
#include <hip/hip_runtime.h>
#include <float.h>

#define B_ROWS 32768
#define C_CODES 4096
#define DDIM 128
#define MB 128            // x-rows per gemm block
#define NCHUNKS 4         // code chunks (grid.y)
#define CCHUNK 1024
#define CTILE 64          // codes per LDS tile
#define NTILES 16         // CCHUNK / CTILE
#define ROWB 256          // bytes per fp16 row

typedef __attribute__((ext_vector_type(16))) float f32x16;
using half8 = __attribute__((ext_vector_type(8))) _Float16;
typedef unsigned int u32;
typedef unsigned short u16;
typedef unsigned long long u64;

__device__ __forceinline__ u16 f2h(float f) {
    return __builtin_bit_cast(u16, (_Float16)f);
}

__device__ __forceinline__ void gl2lds16(const void* g, void* l) {
    __builtin_amdgcn_global_load_lds(
        (const __attribute__((address_space(1))) u32*)g,
        (__attribute__((address_space(3))) u32*)l, 16, 0, 0);
}

// ---------------- fused prep ----------------
// blocks [0,1024):    codes -> fp16 swizzled Bbig + exact fp32 csqh
// blocks [1024,1088): codes -> codesT (fp32 transpose, for recheck)
// blocks [1088,1344): x -> fp16 swizzled Axf16 (pre-swizzled A relay) + xsq2 half-row sums
__global__ void prep_fused(const float* __restrict__ codes, const float* __restrict__ x,
                           u16* __restrict__ Bbig, float* __restrict__ csqh,
                           float* __restrict__ codesT, u16* __restrict__ Axf16,
                           float* __restrict__ xsq2) {
    const int tid = threadIdx.x;
    if (blockIdx.x < C_CODES / 4) {
        const int w = tid >> 6, lane = tid & 63;
        const int c = blockIdx.x * 4 + w;
        const float2 v = ((const float2*)(codes + (size_t)c * DDIM))[lane];
        ushort2 b; b.x = f2h(v.x); b.y = f2h(v.y);
        const int sw = (c & 15) << 4;
        *(ushort2*)((char*)Bbig + (size_t)c * ROWB + ((lane * 4) ^ sw)) = b;
        float s = v.x * v.x + v.y * v.y;
        #pragma unroll
        for (int off = 32; off; off >>= 1) s += __shfl_xor(s, off);
        if (lane == 0) csqh[c] = 0.5f * s;
    } else if (blockIdx.x < C_CODES / 4 + 64) {
        const int g = (blockIdx.x - C_CODES / 4) * 256 + tid;   // 16384 threads
        const int d = g & 127;
        const int cg = g >> 7;                          // 128 groups of 32 codes
        float buf[32];
        #pragma unroll
        for (int k = 0; k < 32; ++k)
            buf[k] = codes[(size_t)(cg * 32 + k) * DDIM + d];
        #pragma unroll
        for (int i = 0; i < 8; ++i) {
            float4 v;
            v.x = buf[i * 4]; v.y = buf[i * 4 + 1]; v.z = buf[i * 4 + 2]; v.w = buf[i * 4 + 3];
            *(float4*)&codesT[(size_t)d * C_CODES + cg * 32 + i * 4] = v;
        }
    } else {
        const int xb = blockIdx.x - (C_CODES / 4 + 64);
        const int r = xb * 128 + (tid >> 1), h = tid & 1;
        const float4* xp = (const float4*)(x + (size_t)r * DDIM + h * 64);
        char* Arow = (char*)Axf16 + (size_t)r * ROWB;
        const int sw = (r & 15) << 4;
        float ss = 0.f;
        #pragma unroll
        for (int i = 0; i < 16; ++i) {
            const float4 v = xp[i];
            ss += v.x * v.x + v.y * v.y + v.z * v.z + v.w * v.w;
            uint2 pk;
            pk.x = (u32)f2h(v.x) | ((u32)f2h(v.y) << 16);
            pk.y = (u32)f2h(v.z) | ((u32)f2h(v.w) << 16);
            *(uint2*)(Arow + ((h * 128 + i * 8) ^ sw)) = pk;
        }
        xsq2[(size_t)r * 2 + h] = ss;   // pair-summed in select_flag
    }
}

// ---------------- fused fp16 MFMA GEMM + per-row top2 (branchless) ----------------
// R13's proven main loop; A arrives pre-converted/pre-swizzled via gl2lds (cheap prologue),
// LDS 36.9KB (A relay overlaps B dbuf) + grid 1024 -> 4 blocks/CU candidate residency.
// launch_bounds stays (256,2): harder caps caused R6/R12 spill storms (unified VGPR/AGPR).
__global__ __launch_bounds__(256, 2)
void gemm_top2(const u16* __restrict__ Axf16, const u16* __restrict__ Bbig,
               const float* __restrict__ csqh,
               float* __restrict__ pb1, float* __restrict__ pb2,
               int* __restrict__ pi1) {
    __shared__ char smem[32768 + 4096];   // A relay (32K, overlaps 2x16K B dbuf) | -csq (4K)
    float* const csq_l = (float*)(smem + 32768);

    const int tid = threadIdx.x;
    const int lane = tid & 63;
    const int w = tid >> 6;
    const int blkrow = blockIdx.x * MB;
    const int cbase = blockIdx.y * CCHUNK;

    // ---- stage negated csq chunk (1024 floats) ----
    {
        const float4 v = ((const float4*)(csqh + cbase))[tid];
        float4 n; n.x = -v.x; n.y = -v.y; n.z = -v.z; n.w = -v.w;
        ((float4*)csq_l)[tid] = n;
    }
    // ---- stage pre-swizzled A tile (32KB) via gl2lds ----
    {
        const char* src = (const char*)Axf16 + (size_t)blkrow * ROWB;
        #pragma unroll
        for (int j = 0; j < 8; ++j)
            gl2lds16(src + j * 4096 + tid * 16, smem + j * 4096 + tid * 16);
    }
    __syncthreads();   // A landed (full vmcnt drain at barrier)

    // ---- load A fragments (8 ksteps) into registers ----
    const int col0 = lane & 31;
    const int khalf = (lane >> 5) << 4;        // 0 or 16 bytes (k-half)
    half8 afr[8];
    {
        const int arow = w * 32 + col0;
        const char* Ab = smem + arow * ROWB;
        const int swa = (arow & 15) << 4;
        #pragma unroll
        for (int ks = 0; ks < 8; ++ks)
            afr[ks] = *(const half8*)(Ab + ((ks * 32 + khalf) ^ swa));
    }
    __syncthreads();   // afr reads done -> A region reusable as B double-buffer

    // ---- stage B tile 0 ----
    {
        const char* src = (const char*)Bbig + (size_t)cbase * ROWB;
        #pragma unroll
        for (int r = 0; r < 4; ++r)
            gl2lds16(src + r * 4096 + w * 1024 + lane * 16, smem + r * 4096 + w * 1024);
    }
    __syncthreads();

    float b1v[16], b2v[16]; int b1i[16];
    #pragma unroll
    for (int r = 0; r < 16; ++r) { b1v[r] = -FLT_MAX; b2v[r] = -FLT_MAX; b1i[r] = 0; }

    const int swb = (col0 & 15) << 4;

    for (int t = 0; t < NTILES; ++t) {
        if (t + 1 < NTILES) {
            char* dbuf = smem + ((t + 1) & 1) * 16384;
            const char* src = (const char*)Bbig + (size_t)(cbase + (t + 1) * CTILE) * ROWB;
            #pragma unroll
            for (int r = 0; r < 4; ++r)
                gl2lds16(src + r * 4096 + w * 1024 + lane * 16, dbuf + r * 4096 + w * 1024);
        }
        const char* Bl = smem + (t & 1) * 16384 + col0 * ROWB;

        const float cs0 = csq_l[t * CTILE + col0];        // already negated
        const float cs1 = csq_l[t * CTILE + 32 + col0];
        f32x16 acc0, acc1;
        #pragma unroll
        for (int i = 0; i < 16; ++i) { acc0[i] = cs0; acc1[i] = cs1; }
        __builtin_amdgcn_s_setprio(1);
        #pragma unroll
        for (int ks = 0; ks < 8; ++ks) {
            const int z = (ks * 32 + khalf) ^ swb;
            const half8 bf0 = *(const half8*)(Bl + z);
            const half8 bf1 = *(const half8*)(Bl + 8192 + z);
            acc0 = __builtin_amdgcn_mfma_f32_32x32x16_f16(afr[ks], bf0, acc0, 0, 0, 0);
            acc1 = __builtin_amdgcn_mfma_f32_32x32x16_f16(afr[ks], bf1, acc1, 0, 0, 0);
        }
        __builtin_amdgcn_s_setprio(0);
        const int idx0 = cbase + t * CTILE + col0;
        const int idx1 = idx0 + 32;
        #pragma unroll
        for (int r = 0; r < 16; ++r) {
            const float s0 = acc0[r];
            const float s1 = acc1[r];
            const float m2a = __builtin_amdgcn_fmed3f(b1v[r], b2v[r], s0);
            const int   nia = (s0 > b1v[r]) ? idx0 : b1i[r];
            const float n1a = fmaxf(b1v[r], s0);
            b2v[r] = __builtin_amdgcn_fmed3f(n1a, m2a, s1);
            b1i[r] = (s1 > n1a) ? idx1 : nia;
            b1v[r] = fmaxf(n1a, s1);
        }
        __syncthreads();
    }

    // ---- merge across the 32 lanes of each half (disjoint code sets, same rows) ----
    #pragma unroll
    for (int off = 1; off <= 16; off <<= 1) {
        #pragma unroll
        for (int r = 0; r < 16; ++r) {
            const float o1 = __shfl_xor(b1v[r], off);
            const int   oi = __shfl_xor(b1i[r], off);
            const float o2 = __shfl_xor(b2v[r], off);
            const float lo = fminf(b1v[r], o1);
            const float nb2 = fmaxf(lo, fmaxf(b2v[r], o2));
            const bool take = (o1 > b1v[r]) || (o1 == b1v[r] && oi < b1i[r]);
            if (take) { b1v[r] = o1; b1i[r] = oi; }
            b2v[r] = nb2;
        }
    }
    if (col0 == 0) {
        const int hi = lane >> 5;
        #pragma unroll
        for (int r = 0; r < 16; ++r) {
            const int rloc = w * 32 + (r & 3) + 8 * (r >> 2) + 4 * hi;
            const int grow = blkrow + rloc;
            const size_t o = (size_t)blockIdx.y * B_ROWS + grow;
            pb1[o] = b1v[r]; pb2[o] = b2v[r]; pi1[o] = b1i[r];
        }
    }
}

// ---------------- merge 4 chunks, decide flags, compact flagged rows ----------------
__global__ void select_flag(const float* __restrict__ pb1, const float* __restrict__ pb2,
                            const int* __restrict__ pi1, const float* __restrict__ xsq2,
                            int* __restrict__ idxf, int* __restrict__ list, int* __restrict__ cnt,
                            u64* __restrict__ amax64) {
    const int r = blockIdx.x * 256 + threadIdx.x;
    float b1 = pb1[r], b2 = pb2[r]; int bi = pi1[r];
    #pragma unroll
    for (int c = 1; c < NCHUNKS; ++c) {
        const float o1 = pb1[(size_t)c * B_ROWS + r], o2 = pb2[(size_t)c * B_ROWS + r];
        const int oi = pi1[(size_t)c * B_ROWS + r];
        const float lo = fminf(b1, o1);
        b2 = fmaxf(lo, fmaxf(b2, o2));
        const bool take = (o1 > b1) || (o1 == b1 && oi < bi);
        if (take) { b1 = o1; bi = oi; }
    }
    idxf[r] = bi;
    const float xsq = xsq2[2 * r] + xsq2[2 * r + 1];
    const float margin = 0.004f * sqrtf(xsq) + 0.008f;
    const bool flag = (b1 - b2) < margin;
    const unsigned long long m = __ballot(flag);
    const int lane = threadIdx.x & 63;
    int base = 0;
    const int nw = __popcll(m);
    if (lane == 0 && nw) base = atomicAdd(cnt, nw);
    base = __shfl(base, 0);
    if (flag) {
        const int pos = base + (int)__popcll(m & ((1ull << lane) - 1ull));
        list[pos] = r;
        amax64[pos] = 0ull;
    }
}

// ---------------- exact fp32 re-resolve: task = (8-row block) x (512-code chunk) ----------------
__global__ __launch_bounds__(256)
void recheck2(const float* __restrict__ x, const float* __restrict__ codesT,
              const float* __restrict__ csqh, const int* __restrict__ list,
              const int* __restrict__ cnt, u64* __restrict__ amax64) {
    __shared__ float xT[128][8];
    __shared__ u64 warr[4][8];
    const int tid = threadIdx.x;
    const int lane = tid & 63, w = tid >> 6;
    const int n = *cnt;
    if (n == 0) return;
    const int ntasks = ((n + 7) >> 3) << 3;

    for (int task = blockIdx.x; task < ntasks; task += gridDim.x) {
        const int slotbase = (task >> 3) << 3;
        const int ch = task & 7;
        __syncthreads();
        #pragma unroll
        for (int k = 0; k < 4; ++k) {
            const int i = tid + k * 256;
            const int d = i & 127, j = i >> 7;
            const int slot = min(slotbase + j, n - 1);
            xT[d][j] = x[(size_t)list[slot] * DDIM + d];
        }
        __syncthreads();

        const int c0 = ch * 512 + tid;
        const int c1 = c0 + 256;
        float acc[2][8][4];
        #pragma unroll
        for (int cc = 0; cc < 2; ++cc)
            #pragma unroll
            for (int r = 0; r < 8; ++r)
                #pragma unroll
                for (int p = 0; p < 4; ++p) acc[cc][r][p] = 0.f;

        for (int d4 = 0; d4 < 32; ++d4) {
            #pragma unroll
            for (int p = 0; p < 4; ++p) {
                const int d = d4 * 4 + p;
                const float cv0 = codesT[(size_t)d * C_CODES + c0];
                const float cv1 = codesT[(size_t)d * C_CODES + c1];
                const float4 xa = *(const float4*)&xT[d][0];
                const float4 xb = *(const float4*)&xT[d][4];
                acc[0][0][p] = fmaf(cv0, xa.x, acc[0][0][p]);
                acc[0][1][p] = fmaf(cv0, xa.y, acc[0][1][p]);
                acc[0][2][p] = fmaf(cv0, xa.z, acc[0][2][p]);
                acc[0][3][p] = fmaf(cv0, xa.w, acc[0][3][p]);
                acc[0][4][p] = fmaf(cv0, xb.x, acc[0][4][p]);
                acc[0][5][p] = fmaf(cv0, xb.y, acc[0][5][p]);
                acc[0][6][p] = fmaf(cv0, xb.z, acc[0][6][p]);
                acc[0][7][p] = fmaf(cv0, xb.w, acc[0][7][p]);
                acc[1][0][p] = fmaf(cv1, xa.x, acc[1][0][p]);
                acc[1][1][p] = fmaf(cv1, xa.y, acc[1][1][p]);
                acc[1][2][p] = fmaf(cv1, xa.z, acc[1][2][p]);
                acc[1][3][p] = fmaf(cv1, xa.w, acc[1][3][p]);
                acc[1][4][p] = fmaf(cv1, xb.x, acc[1][4][p]);
                acc[1][5][p] = fmaf(cv1, xb.y, acc[1][5][p]);
                acc[1][6][p] = fmaf(cv1, xb.z, acc[1][6][p]);
                acc[1][7][p] = fmaf(cv1, xb.w, acc[1][7][p]);
            }
        }

        const float cq0 = csqh[c0], cq1 = csqh[c1];
        #pragma unroll
        for (int r = 0; r < 8; ++r) {
            const float s0 = (acc[0][r][0] + acc[0][r][1]) + (acc[0][r][2] + acc[0][r][3]) - cq0;
            const float s1 = (acc[1][r][0] + acc[1][r][1]) + (acc[1][r][2] + acc[1][r][3]) - cq1;
            const float sb = (s1 > s0) ? s1 : s0;
            const int ib = (s1 > s0) ? c1 : c0;
            u32 su = __float_as_uint(sb);
            su ^= (sb < 0.f) ? 0xFFFFFFFFu : 0x80000000u;
            u64 key = ((u64)su << 32) | (u32)(4095 - ib);
            #pragma unroll
            for (int off = 1; off < 64; off <<= 1) {
                const u64 o = __shfl_xor(key, off);
                key = (o > key) ? o : key;
            }
            if (lane == 0) warr[w][r] = key;
        }
        __syncthreads();
        if (tid < 8) {
            const u64 k01 = warr[0][tid] > warr[1][tid] ? warr[0][tid] : warr[1][tid];
            const u64 k23 = warr[2][tid] > warr[3][tid] ? warr[2][tid] : warr[3][tid];
            const u64 k = k01 > k23 ? k01 : k23;
            atomicMax(&amax64[min(slotbase + tid, n - 1)], k);
        }
    }
}

__global__ void merge_flag(const int* __restrict__ list, const int* __restrict__ cnt,
                           const u64* __restrict__ amax64, int* __restrict__ idxf) {
    const int n = *cnt;
    for (int i = blockIdx.x * 256 + threadIdx.x; i < n; i += gridDim.x * 256)
        idxf[list[i]] = 4095 - (int)(amax64[i] & 0xFFFFFFFFull);
}

// ---------------- gather + outputs + per-block loss partials ----------------
__global__ void finalize(const float* __restrict__ x, const float* __restrict__ codes,
                         const int* __restrict__ idxf, float* __restrict__ qout,
                         float* __restrict__ idxout, float* __restrict__ partials) {
    __shared__ float ls[4];
    const int w = threadIdx.x >> 6, lane = threadIdx.x & 63;
    const int rb = blockIdx.x * 16 + w * 4;
    float wsum = 0.f;
    #pragma unroll
    for (int j = 0; j < 4; ++j) {
        const int r = rb + j;
        const int bi = idxf[r];
        const float2 xv = ((const float2*)(x + (size_t)r * DDIM))[lane];
        const float2 cv = ((const float2*)(codes + (size_t)bi * DDIM))[lane];
        ((float2*)(qout + (size_t)r * DDIM))[lane] = cv;
        if (lane == 0) idxout[r] = (float)bi;
        const float dx = xv.x - cv.x, dy = xv.y - cv.y;
        wsum += dx * dx + dy * dy;
    }
    #pragma unroll
    for (int off = 32; off; off >>= 1) wsum += __shfl_xor(wsum, off);
    if (lane == 0) ls[w] = wsum;
    __syncthreads();
    if (threadIdx.x == 0) partials[blockIdx.x] = (ls[0] + ls[1]) + (ls[2] + ls[3]);
}

__global__ void loss_reduce(const float* __restrict__ partials, float* __restrict__ loss) {
    __shared__ float ls[4];
    const int tid = threadIdx.x, w = tid >> 6, lane = tid & 63;
    float s = 0.f;
    for (int i = tid; i < 2048; i += 256) s += partials[i];
    #pragma unroll
    for (int off = 32; off; off >>= 1) s += __shfl_xor(s, off);
    if (lane == 0) ls[w] = s;
    __syncthreads();
    if (tid == 0) *loss = ((ls[0] + ls[1]) + (ls[2] + ls[3])) * (1.25f / (float)B_ROWS);
}

extern "C" void kernel_launch(void* const* d_in, const int* in_sizes, int n_in,
                              void* d_out, int out_size, void* d_ws, size_t ws_size,
                              hipStream_t stream) {
    const float* x = (const float*)d_in[0];
    const float* codes = (const float*)d_in[1];

    float* out = (float*)d_out;
    float* qout = out;
    float* idxout = out + (size_t)B_ROWS * DDIM;
    float* loss = idxout + B_ROWS;

    // codesT (2MB) and Axf16 (8MB) live in the not-yet-written qout region (16MB);
    // both are fully rewritten by prep each launch, and finalize overwrites qout afterwards.
    float* codesT = qout;
    u16* Axf16 = (u16*)(qout + 524288);   // byte offset 2MB

    char* ws = (char*)d_ws;
    u16* Bbig     = (u16*)ws;                          // 1 MB
    float* csqh   = (float*)(ws + 1048576);            // 16 KB
    float* pb1    = (float*)(ws + 1064960);            // 512 KB (4 chunks)
    float* pb2    = (float*)(ws + 1589248);            // 512 KB
    int* pi1      = (int*)(ws + 2113536);              // 512 KB
    float* xsq2   = (float*)(ws + 2637824);            // 256 KB (2 per row)
    int* idxf     = (int*)(ws + 2899968);              // 128 KB
    int* list     = (int*)(ws + 3031040);              // 128 KB
    int* cnt      = (int*)(ws + 3162112);              // 4 B (+pad)
    float* partials = (float*)(ws + 3162240);          // 8 KB
    u64* amax64   = (u64*)(ws + 3170432);              // 256 KB

    hipMemsetAsync(cnt, 0, 4, stream);
    prep_fused<<<C_CODES / 4 + 64 + B_ROWS / 128, 256, 0, stream>>>(
        codes, x, Bbig, csqh, codesT, Axf16, xsq2);
    gemm_top2<<<dim3(B_ROWS / MB, NCHUNKS), 256, 0, stream>>>(Axf16, Bbig, csqh, pb1, pb2, pi1);
    select_flag<<<B_ROWS / 256, 256, 0, stream>>>(pb1, pb2, pi1, xsq2, idxf, list, cnt, amax64);
    recheck2<<<2048, 256, 0, stream>>>(x, codesT, csqh, list, cnt, amax64);
    merge_flag<<<64, 256, 0, stream>>>(list, cnt, amax64, idxf);
    finalize<<<B_ROWS / 16, 256, 0, stream>>>(x, codes, idxf, qout, idxout, partials);
    loss_reduce<<<1, 256, 0, stream>>>(partials, loss);
}

// Round 15
// 115.419 us; speedup vs baseline: 1.1333x; 1.1333x over previous
//
#include <hip/hip_runtime.h>
#include <float.h>

#define B_ROWS 32768
#define C_CODES 4096
#define DDIM 128
#define MB 128            // x-rows per gemm block
#define NCHUNKS 2         // code chunks (grid.y)
#define CCHUNK 2048
#define CTILE 64          // codes per LDS tile
#define NTILES 32         // CCHUNK / CTILE
#define ROWB 256          // bytes per fp16 row

typedef __attribute__((ext_vector_type(16))) float f32x16;
using half8 = __attribute__((ext_vector_type(8))) _Float16;
typedef unsigned int u32;
typedef unsigned short u16;
typedef unsigned long long u64;

__device__ __forceinline__ u16 f2h(float f) {
    return __builtin_bit_cast(u16, (_Float16)f);
}

__device__ __forceinline__ void gl2lds16(const void* g, void* l) {
    __builtin_amdgcn_global_load_lds(
        (const __attribute__((address_space(1))) u32*)g,
        (__attribute__((address_space(3))) u32*)l, 16, 0, 0);
}

// ---------------- fused prep: codes -> fp16 swizzled Bbig + csqh ; codes -> codesT ----------------
__global__ void prep_fused(const float* __restrict__ codes, u16* __restrict__ Bbig,
                           float* __restrict__ csqh, float* __restrict__ codesT) {
    if (blockIdx.x < C_CODES / 4) {
        const int w = threadIdx.x >> 6, lane = threadIdx.x & 63;
        const int c = blockIdx.x * 4 + w;
        const float2 v = ((const float2*)(codes + (size_t)c * DDIM))[lane];
        ushort2 b; b.x = f2h(v.x); b.y = f2h(v.y);
        const int sw = (c & 15) << 4;
        *(ushort2*)((char*)Bbig + (size_t)c * ROWB + ((lane * 4) ^ sw)) = b;
        float s = v.x * v.x + v.y * v.y;
        #pragma unroll
        for (int off = 32; off; off >>= 1) s += __shfl_xor(s, off);
        if (lane == 0) csqh[c] = 0.5f * s;
    } else {
        const int g = (blockIdx.x - C_CODES / 4) * 256 + threadIdx.x;   // 16384 threads
        const int d = g & 127;
        const int cg = g >> 7;                          // 128 groups of 32 codes
        float buf[32];
        #pragma unroll
        for (int k = 0; k < 32; ++k)
            buf[k] = codes[(size_t)(cg * 32 + k) * DDIM + d];
        #pragma unroll
        for (int i = 0; i < 8; ++i) {
            float4 v;
            v.x = buf[i * 4]; v.y = buf[i * 4 + 1]; v.z = buf[i * 4 + 2]; v.w = buf[i * 4 + 3];
            *(float4*)&codesT[(size_t)d * C_CODES + cg * 32 + i * 4] = v;
        }
    }
}

// ---------------- fused fp16 MFMA GEMM + per-row top2 (branchless) ----------------
// Best measured configuration (R13, total 115.7us; gemm 72us): 2x16KB B double-buffer,
// separate A-stage, csq folded into acc init, fmed3/fmax branchless top-2 epilogue.
// launch_bounds stays (256,2): harder caps caused R6/R12 spill storms (unified VGPR/AGPR).
// Structure plateau: 5 schedule variants (dbuf/overlap/counted-vmcnt/ping-pong/dual-chain)
// all land 72-88us; occupancy pinned ~19% regardless of LDS/grid (R14 deconfounded test).
__global__ __launch_bounds__(256, 2)
void gemm_top2(const float* __restrict__ x, const u16* __restrict__ Bbig,
               const float* __restrict__ csqh,
               float* __restrict__ pb1, float* __restrict__ pb2,
               int* __restrict__ pi1, float* __restrict__ xsq_ws) {
    __shared__ char smem[2 * 16384 + 32768 + 8192 + 1024];  // B dbuf | A swz | -csq | xsq
    char* const Areg = smem + 32768;
    float* const csq_l = (float*)(smem + 65536);
    float* const xsqArr = (float*)(smem + 65536 + 8192);

    const int tid = threadIdx.x;
    const int lane = tid & 63;
    const int w = tid >> 6;
    const int blkrow = blockIdx.x * MB;
    const int cbase = blockIdx.y * CCHUNK;

    // ---- stage negated csq chunk to LDS ----
    {
        const float4* cs = (const float4*)(csqh + cbase);
        #pragma unroll
        for (int j = 0; j < 2; ++j) {
            const float4 v = cs[j * 256 + tid];
            float4 n; n.x = -v.x; n.y = -v.y; n.z = -v.z; n.w = -v.w;
            ((float4*)csq_l)[j * 256 + tid] = n;
        }
    }
    // ---- convert this block's 128 x-rows to fp16, swizzled, into LDS; xsq partials ----
    {
        const int r = tid >> 1, h = tid & 1;
        const float4* xp = (const float4*)(x + (size_t)(blkrow + r) * DDIM + h * 64);
        char* Arow = Areg + r * ROWB;
        const int sw = (r & 15) << 4;
        float ss = 0.f;
        #pragma unroll
        for (int i = 0; i < 16; ++i) {
            const float4 v = xp[i];
            ss += v.x * v.x + v.y * v.y + v.z * v.z + v.w * v.w;
            uint2 pk;
            pk.x = (u32)f2h(v.x) | ((u32)f2h(v.y) << 16);
            pk.y = (u32)f2h(v.z) | ((u32)f2h(v.w) << 16);
            *(uint2*)(Arow + ((h * 128 + i * 8) ^ sw)) = pk;
        }
        xsqArr[tid] = ss;
    }
    // stage B tile 0
    {
        const char* src = (const char*)Bbig + (size_t)cbase * ROWB;
        #pragma unroll
        for (int r = 0; r < 4; ++r)
            gl2lds16(src + r * 4096 + w * 1024 + lane * 16, smem + r * 4096 + w * 1024);
    }
    __syncthreads();

    // ---- load A fragments (8 ksteps) into registers ----
    const int col0 = lane & 31;
    const int khalf = (lane >> 5) << 4;        // 0 or 16 bytes (k-half)
    half8 afr[8];
    {
        const int arow = w * 32 + col0;
        const char* Ab = Areg + arow * ROWB;
        const int swa = (arow & 15) << 4;
        #pragma unroll
        for (int ks = 0; ks < 8; ++ks)
            afr[ks] = *(const half8*)(Ab + ((ks * 32 + khalf) ^ swa));
    }

    float b1v[16], b2v[16]; int b1i[16];
    #pragma unroll
    for (int r = 0; r < 16; ++r) { b1v[r] = -FLT_MAX; b2v[r] = -FLT_MAX; b1i[r] = 0; }

    const int swb = (col0 & 15) << 4;

    for (int t = 0; t < NTILES; ++t) {
        if (t + 1 < NTILES) {
            char* dbuf = smem + ((t + 1) & 1) * 16384;
            const char* src = (const char*)Bbig + (size_t)(cbase + (t + 1) * CTILE) * ROWB;
            #pragma unroll
            for (int r = 0; r < 4; ++r)
                gl2lds16(src + r * 4096 + w * 1024 + lane * 16, dbuf + r * 4096 + w * 1024);
        }
        const char* Bl = smem + (t & 1) * 16384 + col0 * ROWB;

        const float cs0 = csq_l[t * CTILE + col0];        // already negated
        const float cs1 = csq_l[t * CTILE + 32 + col0];
        f32x16 acc0, acc1;
        #pragma unroll
        for (int i = 0; i < 16; ++i) { acc0[i] = cs0; acc1[i] = cs1; }
        __builtin_amdgcn_s_setprio(1);
        #pragma unroll
        for (int ks = 0; ks < 8; ++ks) {
            const int z = (ks * 32 + khalf) ^ swb;
            const half8 bf0 = *(const half8*)(Bl + z);
            const half8 bf1 = *(const half8*)(Bl + 8192 + z);
            acc0 = __builtin_amdgcn_mfma_f32_32x32x16_f16(afr[ks], bf0, acc0, 0, 0, 0);
            acc1 = __builtin_amdgcn_mfma_f32_32x32x16_f16(afr[ks], bf1, acc1, 0, 0, 0);
        }
        __builtin_amdgcn_s_setprio(0);
        const int idx0 = cbase + t * CTILE + col0;
        const int idx1 = idx0 + 32;
        #pragma unroll
        for (int r = 0; r < 16; ++r) {
            const float s0 = acc0[r];
            const float s1 = acc1[r];
            const float m2a = __builtin_amdgcn_fmed3f(b1v[r], b2v[r], s0);
            const int   nia = (s0 > b1v[r]) ? idx0 : b1i[r];
            const float n1a = fmaxf(b1v[r], s0);
            b2v[r] = __builtin_amdgcn_fmed3f(n1a, m2a, s1);
            b1i[r] = (s1 > n1a) ? idx1 : nia;
            b1v[r] = fmaxf(n1a, s1);
        }
        __syncthreads();
    }

    // ---- merge across the 32 lanes of each half (disjoint code sets, same rows) ----
    #pragma unroll
    for (int off = 1; off <= 16; off <<= 1) {
        #pragma unroll
        for (int r = 0; r < 16; ++r) {
            const float o1 = __shfl_xor(b1v[r], off);
            const int   oi = __shfl_xor(b1i[r], off);
            const float o2 = __shfl_xor(b2v[r], off);
            const float lo = fminf(b1v[r], o1);
            const float nb2 = fmaxf(lo, fmaxf(b2v[r], o2));
            const bool take = (o1 > b1v[r]) || (o1 == b1v[r] && oi < b1i[r]);
            if (take) { b1v[r] = o1; b1i[r] = oi; }
            b2v[r] = nb2;
        }
    }
    if (col0 == 0) {
        const int hi = lane >> 5;
        #pragma unroll
        for (int r = 0; r < 16; ++r) {
            const int rloc = w * 32 + (r & 3) + 8 * (r >> 2) + 4 * hi;
            const int grow = blkrow + rloc;
            const size_t o = (size_t)blockIdx.y * B_ROWS + grow;
            pb1[o] = b1v[r]; pb2[o] = b2v[r]; pi1[o] = b1i[r];
            if (blockIdx.y == 0)
                xsq_ws[grow] = xsqArr[2 * rloc] + xsqArr[2 * rloc + 1];
        }
    }
}

// ---------------- merge 2 chunks, decide flags, compact flagged rows ----------------
__global__ void select_flag(const float* __restrict__ pb1, const float* __restrict__ pb2,
                            const int* __restrict__ pi1, const float* __restrict__ xsq_ws,
                            int* __restrict__ idxf, int* __restrict__ list, int* __restrict__ cnt,
                            u64* __restrict__ amax64) {
    const int r = blockIdx.x * 256 + threadIdx.x;
    const float a1 = pb1[r], a2 = pb2[r]; const int ai = pi1[r];
    const float o1 = pb1[B_ROWS + r], o2 = pb2[B_ROWS + r]; const int oi = pi1[B_ROWS + r];
    const float lo = fminf(a1, o1);
    const float nb2 = fmaxf(lo, fmaxf(a2, o2));
    const bool take = (o1 > a1) || (o1 == a1 && oi < ai);
    const float b1 = take ? o1 : a1;
    const int bi = take ? oi : ai;
    idxf[r] = bi;
    const float margin = 0.004f * sqrtf(xsq_ws[r]) + 0.008f;
    const bool flag = (b1 - nb2) < margin;
    const unsigned long long m = __ballot(flag);
    const int lane = threadIdx.x & 63;
    int base = 0;
    const int nw = __popcll(m);
    if (lane == 0 && nw) base = atomicAdd(cnt, nw);
    base = __shfl(base, 0);
    if (flag) {
        const int pos = base + (int)__popcll(m & ((1ull << lane) - 1ull));
        list[pos] = r;
        amax64[pos] = 0ull;
    }
}

// ---------------- exact fp32 re-resolve: task = (8-row block) x (512-code chunk) ----------------
__global__ __launch_bounds__(256)
void recheck2(const float* __restrict__ x, const float* __restrict__ codesT,
              const float* __restrict__ csqh, const int* __restrict__ list,
              const int* __restrict__ cnt, u64* __restrict__ amax64) {
    __shared__ float xT[128][8];
    __shared__ u64 warr[4][8];
    const int tid = threadIdx.x;
    const int lane = tid & 63, w = tid >> 6;
    const int n = *cnt;
    if (n == 0) return;
    const int ntasks = ((n + 7) >> 3) << 3;

    for (int task = blockIdx.x; task < ntasks; task += gridDim.x) {
        const int slotbase = (task >> 3) << 3;
        const int ch = task & 7;
        __syncthreads();
        #pragma unroll
        for (int k = 0; k < 4; ++k) {
            const int i = tid + k * 256;
            const int d = i & 127, j = i >> 7;
            const int slot = min(slotbase + j, n - 1);
            xT[d][j] = x[(size_t)list[slot] * DDIM + d];
        }
        __syncthreads();

        const int c0 = ch * 512 + tid;
        const int c1 = c0 + 256;
        float acc[2][8][4];
        #pragma unroll
        for (int cc = 0; cc < 2; ++cc)
            #pragma unroll
            for (int r = 0; r < 8; ++r)
                #pragma unroll
                for (int p = 0; p < 4; ++p) acc[cc][r][p] = 0.f;

        for (int d4 = 0; d4 < 32; ++d4) {
            #pragma unroll
            for (int p = 0; p < 4; ++p) {
                const int d = d4 * 4 + p;
                const float cv0 = codesT[(size_t)d * C_CODES + c0];
                const float cv1 = codesT[(size_t)d * C_CODES + c1];
                const float4 xa = *(const float4*)&xT[d][0];
                const float4 xb = *(const float4*)&xT[d][4];
                acc[0][0][p] = fmaf(cv0, xa.x, acc[0][0][p]);
                acc[0][1][p] = fmaf(cv0, xa.y, acc[0][1][p]);
                acc[0][2][p] = fmaf(cv0, xa.z, acc[0][2][p]);
                acc[0][3][p] = fmaf(cv0, xa.w, acc[0][3][p]);
                acc[0][4][p] = fmaf(cv0, xb.x, acc[0][4][p]);
                acc[0][5][p] = fmaf(cv0, xb.y, acc[0][5][p]);
                acc[0][6][p] = fmaf(cv0, xb.z, acc[0][6][p]);
                acc[0][7][p] = fmaf(cv0, xb.w, acc[0][7][p]);
                acc[1][0][p] = fmaf(cv1, xa.x, acc[1][0][p]);
                acc[1][1][p] = fmaf(cv1, xa.y, acc[1][1][p]);
                acc[1][2][p] = fmaf(cv1, xa.z, acc[1][2][p]);
                acc[1][3][p] = fmaf(cv1, xa.w, acc[1][3][p]);
                acc[1][4][p] = fmaf(cv1, xb.x, acc[1][4][p]);
                acc[1][5][p] = fmaf(cv1, xb.y, acc[1][5][p]);
                acc[1][6][p] = fmaf(cv1, xb.z, acc[1][6][p]);
                acc[1][7][p] = fmaf(cv1, xb.w, acc[1][7][p]);
            }
        }

        const float cq0 = csqh[c0], cq1 = csqh[c1];
        #pragma unroll
        for (int r = 0; r < 8; ++r) {
            const float s0 = (acc[0][r][0] + acc[0][r][1]) + (acc[0][r][2] + acc[0][r][3]) - cq0;
            const float s1 = (acc[1][r][0] + acc[1][r][1]) + (acc[1][r][2] + acc[1][r][3]) - cq1;
            const float sb = (s1 > s0) ? s1 : s0;
            const int ib = (s1 > s0) ? c1 : c0;
            u32 su = __float_as_uint(sb);
            su ^= (sb < 0.f) ? 0xFFFFFFFFu : 0x80000000u;
            u64 key = ((u64)su << 32) | (u32)(4095 - ib);
            #pragma unroll
            for (int off = 1; off < 64; off <<= 1) {
                const u64 o = __shfl_xor(key, off);
                key = (o > key) ? o : key;
            }
            if (lane == 0) warr[w][r] = key;
        }
        __syncthreads();
        if (tid < 8) {
            const u64 k01 = warr[0][tid] > warr[1][tid] ? warr[0][tid] : warr[1][tid];
            const u64 k23 = warr[2][tid] > warr[3][tid] ? warr[2][tid] : warr[3][tid];
            const u64 k = k01 > k23 ? k01 : k23;
            atomicMax(&amax64[min(slotbase + tid, n - 1)], k);
        }
    }
}

__global__ void merge_flag(const int* __restrict__ list, const int* __restrict__ cnt,
                           const u64* __restrict__ amax64, int* __restrict__ idxf) {
    const int n = *cnt;
    for (int i = blockIdx.x * 256 + threadIdx.x; i < n; i += gridDim.x * 256)
        idxf[list[i]] = 4095 - (int)(amax64[i] & 0xFFFFFFFFull);
}

// ---------------- gather + outputs + per-block loss partials ----------------
__global__ void finalize(const float* __restrict__ x, const float* __restrict__ codes,
                         const int* __restrict__ idxf, float* __restrict__ qout,
                         float* __restrict__ idxout, float* __restrict__ partials) {
    __shared__ float ls[4];
    const int w = threadIdx.x >> 6, lane = threadIdx.x & 63;
    const int rb = blockIdx.x * 16 + w * 4;
    float wsum = 0.f;
    #pragma unroll
    for (int j = 0; j < 4; ++j) {
        const int r = rb + j;
        const int bi = idxf[r];
        const float2 xv = ((const float2*)(x + (size_t)r * DDIM))[lane];
        const float2 cv = ((const float2*)(codes + (size_t)bi * DDIM))[lane];
        ((float2*)(qout + (size_t)r * DDIM))[lane] = cv;
        if (lane == 0) idxout[r] = (float)bi;
        const float dx = xv.x - cv.x, dy = xv.y - cv.y;
        wsum += dx * dx + dy * dy;
    }
    #pragma unroll
    for (int off = 32; off; off >>= 1) wsum += __shfl_xor(wsum, off);
    if (lane == 0) ls[w] = wsum;
    __syncthreads();
    if (threadIdx.x == 0) partials[blockIdx.x] = (ls[0] + ls[1]) + (ls[2] + ls[3]);
}

__global__ void loss_reduce(const float* __restrict__ partials, float* __restrict__ loss) {
    __shared__ float ls[4];
    const int tid = threadIdx.x, w = tid >> 6, lane = tid & 63;
    float s = 0.f;
    for (int i = tid; i < 2048; i += 256) s += partials[i];
    #pragma unroll
    for (int off = 32; off; off >>= 1) s += __shfl_xor(s, off);
    if (lane == 0) ls[w] = s;
    __syncthreads();
    if (tid == 0) *loss = ((ls[0] + ls[1]) + (ls[2] + ls[3])) * (1.25f / (float)B_ROWS);
}

extern "C" void kernel_launch(void* const* d_in, const int* in_sizes, int n_in,
                              void* d_out, int out_size, void* d_ws, size_t ws_size,
                              hipStream_t stream) {
    const float* x = (const float*)d_in[0];
    const float* codes = (const float*)d_in[1];

    float* out = (float*)d_out;
    float* qout = out;
    float* idxout = out + (size_t)B_ROWS * DDIM;
    float* loss = idxout + B_ROWS;

    // codesT lives in the (not-yet-written) qout region; finalize overwrites it afterwards.
    float* codesT = qout;

    char* ws = (char*)d_ws;
    u16* Bbig     = (u16*)ws;                          // 1 MB
    float* csqh   = (float*)(ws + 1048576);            // 16 KB
    float* pb1    = (float*)(ws + 1064960);            // 256 KB (2 chunks)
    float* pb2    = (float*)(ws + 1327104);            // 256 KB
    int* pi1      = (int*)(ws + 1589248);              // 256 KB
    float* xsq_ws = (float*)(ws + 1851392);            // 128 KB
    int* idxf     = (int*)(ws + 1982464);              // 128 KB
    int* list     = (int*)(ws + 2113536);              // 128 KB
    int* cnt      = (int*)(ws + 2244608);              // 4 B (+pad)
    float* partials = (float*)(ws + 2244736);          // 8 KB
    u64* amax64   = (u64*)(ws + 2252800);              // 256 KB

    hipMemsetAsync(cnt, 0, 4, stream);
    prep_fused<<<C_CODES / 4 + 64, 256, 0, stream>>>(codes, Bbig, csqh, codesT);
    gemm_top2<<<dim3(B_ROWS / MB, NCHUNKS), 256, 0, stream>>>(x, Bbig, csqh, pb1, pb2, pi1, xsq_ws);
    select_flag<<<B_ROWS / 256, 256, 0, stream>>>(pb1, pb2, pi1, xsq_ws, idxf, list, cnt, amax64);
    recheck2<<<2048, 256, 0, stream>>>(x, codesT, csqh, list, cnt, amax64);
    merge_flag<<<64, 256, 0, stream>>>(list, cnt, amax64, idxf);
    finalize<<<B_ROWS / 16, 256, 0, stream>>>(x, codes, idxf, qout, idxout, partials);
    loss_reduce<<<1, 256, 0, stream>>>(partials, loss);
}